// Round 4
// baseline (551.145 us; speedup 1.0000x reference)
//
#include <hip/hip_runtime.h>
#include <math.h>

typedef short bf16x8 __attribute__((ext_vector_type(8)));
typedef float f32x4  __attribute__((ext_vector_type(4)));

#define TT 32
#define MM 16
#define CC 128
#define NPT 32768
#define NC 4194304          // NPT*CC, elements per time-slice
#define BN 8                // n-points per block (main kernel)

// ---- LDS layout (bytes), total 79872 (78 KB) -> 2 blocks/CU ----
// XF: bf16 [m16][n8][i128][ri2] = 65536 B, phys = L ^ ((n&7)<<4)
// OF: bf16 [no128][k2_32], padded row stride 80 B = 10240 B
// TABC/TABS: f32 [t32][m16] = 2048 B each
#define XF_OFF   0
#define OF_OFF   65536
#define OF_STRIDE 80
#define TABC_OFF 75776
#define TABS_OFF 77824
#define LDS_BYTES 79872

static __device__ __forceinline__ unsigned short f2bf(float f) {
    union { float f; unsigned u; } v; v.f = f;
    unsigned r = v.u + 0x7FFFu + ((v.u >> 16) & 1u);   // RNE
    return (unsigned short)(r >> 16);
}

// ============================================================================
// Weight repack: w[i][o][m][ri] f32 -> bf16 MFMA B-fragments in d_ws.
// Layout (short8 rows): WB[m][og][riOut][ck][lane]  (16*8*2*8*64 rows) —
// per (m,og) the 16 fragments are CONTIGUOUS (16 KB) for L2 burst reads.
// Row holds B[k = ck*32 + (lane>>4)*8 + j][o = og*16 + (lane&15)], j=0..7,
// where k = 2i+ri_in stacking:  B_R = {+Wr, -Wi},  B_I = {+Wi, +Wr}.
// ============================================================================
__global__ void repack_w(const float* __restrict__ w, bf16x8* __restrict__ wb) {
    int r = blockIdx.x * blockDim.x + threadIdx.x;    // 0..131071
    int lane = r & 63;
    int r2 = r >> 6;
    int ck = r2 & 7;
    int r3 = r2 >> 3;
    int ri = r3 & 1;
    int r4 = r3 >> 1;
    int og = r4 & 7;
    int m  = r4 >> 3;
    int o = og * 16 + (lane & 15);
    int kbase = ck * 32 + (lane >> 4) * 8;
    bf16x8 v;
    #pragma unroll
    for (int j = 0; j < 8; ++j) {
        int k = kbase + j;
        int i = k >> 1, ko = k & 1;
        const float* wp = w + ((size_t)(i * 128 + o) * 16 + m) * 2;
        float val;
        if (ri == 0) val = ko ? -wp[1] : wp[0];
        else         val = ko ?  wp[0] : wp[1];
        v[j] = (short)f2bf(val);
    }
    wb[r] = v;
}

// ============================================================================
// Main fused kernel: 1024 threads = 16 waves. BN=8 n-points per block,
// 4096 blocks, 2 blocks/CU (78 KB LDS, VGPR capped at 64).
// einsum: wave = mode (M-rows 8..15 alias 0..7, outputs discarded).
// irfft: wave pair covers t-halves; per-thread DT fragment via sincosf.
// ============================================================================
__global__ __launch_bounds__(1024, 8)
void spectral_mfma(const float* __restrict__ x, const bf16x8* __restrict__ wb,
                   float* __restrict__ out) {
    extern __shared__ char lds[];
    float* tabc = (float*)(lds + TABC_OFF);
    float* tabs = (float*)(lds + TABS_OFF);
    const int tid = threadIdx.x;
    const int n0  = blockIdx.x * BN;

    // ---------- phase 0: rfft tables, transposed [t][m] ----------
    if (tid < 512) {
        int m = tid & 15, t = tid >> 4;    // t 0..31
        float ang = 0.19634954084936207f * (float)((m * t) & 31);
        float s, c; sincosf(ang, &s, &c);
        tabc[t * 16 + m] = c;
        tabs[t * 16 + m] = s;
    }
    __syncthreads();

    // ---------- phase 1: folded rfft, one i-column per thread ----------
    {
        const int i  = tid & 127;
        const int nn = tid >> 7;           // 0..7
        const float* xp = x + (size_t)(n0 + nn) * CC + i;
        float x0  = xp[0];
        float x16 = xp[(size_t)16 * NC];
        float xr[16], xi[16];
        #pragma unroll
        for (int m = 0; m < 16; ++m) {
            xr[m] = x0 + ((m & 1) ? -x16 : x16);
            xi[m] = 0.f;
        }
        #pragma unroll
        for (int t = 1; t <= 15; ++t) {
            float a = xp[(size_t)t * NC];
            float b = xp[(size_t)(32 - t) * NC];
            float e = a + b, od = a - b;
            #pragma unroll
            for (int mh = 0; mh < 16; mh += 8) {     // halves to cap VGPR
                float4 c0 = *(const float4*)&tabc[t * 16 + mh];
                float4 c1 = *(const float4*)&tabc[t * 16 + mh + 4];
                float4 s0 = *(const float4*)&tabs[t * 16 + mh];
                float4 s1 = *(const float4*)&tabs[t * 16 + mh + 4];
                xr[mh+0] += e * c0.x;  xi[mh+0] -= od * s0.x;
                xr[mh+1] += e * c0.y;  xi[mh+1] -= od * s0.y;
                xr[mh+2] += e * c0.z;  xi[mh+2] -= od * s0.z;
                xr[mh+3] += e * c0.w;  xi[mh+3] -= od * s0.w;
                xr[mh+4] += e * c1.x;  xi[mh+4] -= od * s1.x;
                xr[mh+5] += e * c1.y;  xi[mh+5] -= od * s1.y;
                xr[mh+6] += e * c1.z;  xi[mh+6] -= od * s1.z;
                xr[mh+7] += e * c1.w;  xi[mh+7] -= od * s1.w;
            }
        }
        char* xfb = lds + XF_OFF;
        #pragma unroll
        for (int m = 0; m < 16; ++m) {
            unsigned byte = ((unsigned)(m * 4096 + nn * 512 + i * 4))
                            ^ ((unsigned)(nn & 7) << 4);
            unsigned v = (unsigned)f2bf(xr[m]) | ((unsigned)f2bf(xi[m]) << 16);
            *(unsigned*)(xfb + byte) = v;
        }
    }
    __syncthreads();

    // ---------- phase 2/3: einsum MFMA + irfft MFMA per 16-wide o-tile ----------
    const int lane  = tid & 63;
    const int wid   = tid >> 6;     // einsum: mode; irfft: (t-half, n-chunk)
    const int col   = lane & 15;
    const int kq    = lane >> 4;
    const int thalf = wid >> 3;

    // per-thread irfft fragment DT[t = thalf*16+col][k2 = kq*8+j]
    bf16x8 dtf;
    {
        const int t = thalf * 16 + col;
        #pragma unroll
        for (int jm = 0; jm < 4; ++jm) {
            int m = kq * 4 + jm;
            float alpha = (m == 0) ? 0.03125f : 0.0625f;   // 1/32, 2/32
            float ang = 0.19634954084936207f * (float)((m * t) & 31);
            float s, c; sincosf(ang, &s, &c);
            dtf[jm * 2 + 0] = (short)f2bf(alpha * c);
            dtf[jm * 2 + 1] = (m == 0) ? (short)0 : (short)f2bf(-alpha * s);
        }
    }

    char* xfb = lds + XF_OFF;
    char* ofb = lds + OF_OFF;
    const unsigned arow = (unsigned)(wid * 4096 + (col & 7) * 512 + kq * 16);
    const unsigned aswz = (unsigned)((col & 7) << 4);
    const bf16x8* wbase = wb + (size_t)wid * (8 * 2 * 8 * 64);
    float* outp = out + (size_t)(n0 + (wid & 7)) * CC + col;

    for (int og = 0; og < 8; ++og) {
        // --- einsum: OF[mode=wid] for o-tile og, K=256 over (i,ri) ---
        const bf16x8* wog = wbase + (size_t)og * (2 * 8 * 64);
        f32x4 accR = {0.f, 0.f, 0.f, 0.f};
        f32x4 accI = {0.f, 0.f, 0.f, 0.f};
        #pragma unroll
        for (int ck = 0; ck < 8; ++ck) {
            bf16x8 af = *(const bf16x8*)(xfb + ((arow + (unsigned)(ck * 64)) ^ aswz));
            bf16x8 bR = wog[(0 * 8 + ck) * 64 + lane];
            bf16x8 bI = wog[(1 * 8 + ck) * 64 + lane];
            accR = __builtin_amdgcn_mfma_f32_16x16x32_bf16(af, bR, accR, 0, 0, 0);
            accI = __builtin_amdgcn_mfma_f32_16x16x32_bf16(af, bI, accI, 0, 0, 0);
        }
        // C rows n = kq*4+j; only n<8 valid (rows 8..15 are aliased duplicates)
        if (kq < 2) {
            #pragma unroll
            for (int j = 0; j < 4; ++j) {
                int no = (kq * 4 + j) * 16 + col;
                unsigned v = (unsigned)f2bf(accR[j]) | ((unsigned)f2bf(accI[j]) << 16);
                *(unsigned*)(ofb + no * OF_STRIDE + wid * 4) = v;
            }
        }
        __syncthreads();
        // --- irfft: out[t][n][og*16+col] = DT x OF^T ---
        {
            int no0 = (wid & 7) * 16 + col;
            bf16x8 pf = *(const bf16x8*)(ofb + no0 * OF_STRIDE + kq * 16);
            f32x4 z = {0.f, 0.f, 0.f, 0.f};
            f32x4 cc = __builtin_amdgcn_mfma_f32_16x16x32_bf16(dtf, pf, z, 0, 0, 0);
            float* op = outp + og * 16;
            #pragma unroll
            for (int j = 0; j < 4; ++j) {
                int t0 = thalf * 16 + kq * 4 + j;
                op[(size_t)t0 * NC] = cc[j];
            }
        }
        __syncthreads();   // OF reused next og
    }
}

// ============================================================================
// Fallback (round-1 proven kernel) — used only if ws_size < 2 MB.
// ============================================================================
#define FBN 8
#define FXST 36
__global__ __launch_bounds__(512, 2)
void spectral_fused(const float* __restrict__ x,
                    const float* __restrict__ w,
                    float* __restrict__ out) {
    extern __shared__ float flds[];
    float* xf    = flds;
    float* ftabc = flds + FBN * CC * FXST;
    float* ftabs = ftabc + 512;

    const int tid = threadIdx.x;
    const int n0  = blockIdx.x * FBN;

    {
        const int m = tid >> 5;
        const int t = tid & 31;
        const int k = (m * t) & 31;
        const float ang = 0.19634954084936207f * (float)k;
        float s, c; sincosf(ang, &s, &c);
        ftabc[tid] = c; ftabs[tid] = s;
    }
    __syncthreads();
    {
        const int i   = tid & 127;
        const int nnA = tid >> 7;
        const int nnB = nnA + 4;
        float xra[MM], xia[MM], xrb[MM], xib[MM];
        #pragma unroll
        for (int m = 0; m < MM; ++m) { xra[m]=0.f; xia[m]=0.f; xrb[m]=0.f; xib[m]=0.f; }
        const float* xA = x + (size_t)(n0 + nnA) * CC + i;
        const float* xB = x + (size_t)(n0 + nnB) * CC + i;
        for (int t = 0; t < TT; ++t) {
            const float va = xA[(size_t)t * NC];
            const float vb = xB[(size_t)t * NC];
            #pragma unroll
            for (int m = 0; m < MM; ++m) {
                const float c = ftabc[(m << 5) + t];
                const float s = ftabs[(m << 5) + t];
                xra[m] += va * c;  xia[m] -= va * s;
                xrb[m] += vb * c;  xib[m] -= vb * s;
            }
        }
        float* dA = xf + (size_t)(nnA * CC + i) * FXST;
        float* dB = xf + (size_t)(nnB * CC + i) * FXST;
        #pragma unroll
        for (int j = 0; j < 8; ++j) {
            *(float4*)(dA + 4 * j) = make_float4(xra[2*j], xia[2*j], xra[2*j+1], xia[2*j+1]);
            *(float4*)(dB + 4 * j) = make_float4(xrb[2*j], xib[2*j], xrb[2*j+1], xib[2*j+1]);
        }
    }
    __syncthreads();
    const int o   = tid & 127;
    const int nnA = tid >> 7;
    const int nnB = nnA + 4;
    float ar[MM], ai_[MM], br[MM], bi_[MM];
    #pragma unroll
    for (int m = 0; m < MM; ++m) { ar[m]=0.f; ai_[m]=0.f; br[m]=0.f; bi_[m]=0.f; }
    const float* qa0 = xf + (size_t)(nnA * CC) * FXST;
    const float* qb0 = xf + (size_t)(nnB * CC) * FXST;
    float4 wv[8];
    {
        const float4* wp = (const float4*)(w + (size_t)o * 32);
        #pragma unroll
        for (int j = 0; j < 8; ++j) wv[j] = wp[j];
    }
    for (int i = 0; i < CC; ++i) {
        float4 xa4[8], xb4[8];
        const float4* qa = (const float4*)(qa0 + i * FXST);
        const float4* qb = (const float4*)(qb0 + i * FXST);
        #pragma unroll
        for (int j = 0; j < 8; ++j) { xa4[j] = qa[j]; xb4[j] = qb[j]; }
        float4 wn[8];
        if (i + 1 < CC) {
            const float4* wp = (const float4*)(w + (size_t)((i + 1) * CC + o) * 32);
            #pragma unroll
            for (int j = 0; j < 8; ++j) wn[j] = wp[j];
        }
        #pragma unroll
        for (int j = 0; j < 8; ++j) {
            const int m0 = 2 * j, m1 = 2 * j + 1;
            ar[m0]  += xa4[j].x * wv[j].x - xa4[j].y * wv[j].y;
            ai_[m0] += xa4[j].x * wv[j].y + xa4[j].y * wv[j].x;
            br[m0]  += xb4[j].x * wv[j].x - xb4[j].y * wv[j].y;
            bi_[m0] += xb4[j].x * wv[j].y + xb4[j].y * wv[j].x;
            ar[m1]  += xa4[j].z * wv[j].z - xa4[j].w * wv[j].w;
            ai_[m1] += xa4[j].z * wv[j].w + xa4[j].w * wv[j].z;
            br[m1]  += xb4[j].z * wv[j].z - xb4[j].w * wv[j].w;
            bi_[m1] += xb4[j].z * wv[j].w + xb4[j].w * wv[j].z;
        }
        #pragma unroll
        for (int j = 0; j < 8; ++j) wv[j] = wn[j];
    }
    {
        const float inv = 1.0f / 32.0f;
        const size_t obA = (size_t)(n0 + nnA) * CC + o;
        const size_t obB = (size_t)(n0 + nnB) * CC + o;
        for (int t = 0; t < TT; ++t) {
            float accA = 0.f, accB = 0.f;
            #pragma unroll
            for (int m = 1; m < MM; ++m) {
                const float c = ftabc[(m << 5) + t];
                const float s = ftabs[(m << 5) + t];
                accA += ar[m] * c - ai_[m] * s;
                accB += br[m] * c - bi_[m] * s;
            }
            out[(size_t)t * NC + obA] = (ar[0] + 2.f * accA) * inv;
            out[(size_t)t * NC + obB] = (br[0] + 2.f * accB) * inv;
        }
    }
}

extern "C" void kernel_launch(void* const* d_in, const int* in_sizes, int n_in,
                              void* d_out, int out_size, void* d_ws, size_t ws_size,
                              hipStream_t stream) {
    (void)in_sizes; (void)n_in; (void)out_size;
    const float* x = (const float*)d_in[0];
    const float* w = (const float*)d_in[1];
    float* out     = (float*)d_out;

    if (d_ws != nullptr && ws_size >= (size_t)2 * 1024 * 1024) {
        bf16x8* wbuf = (bf16x8*)d_ws;
        hipLaunchKernelGGL(repack_w, dim3(512), dim3(256), 0, stream, w, wbuf);
        hipLaunchKernelGGL(spectral_mfma, dim3(NPT / BN), dim3(1024), LDS_BYTES, stream,
                           x, wbuf, out);
    } else {
        const size_t lds_bytes = (size_t)(FBN * CC * FXST + 1024) * sizeof(float);
        hipLaunchKernelGGL(spectral_fused, dim3(NPT / FBN), dim3(512), lds_bytes, stream,
                           x, w, out);
    }
}